// Round 5
// baseline (150.085 us; speedup 1.0000x reference)
//
#include <hip/hip_runtime.h>

// Problem constants (fixed by reference setup_inputs):
#define NB    8
#define NA    3
#define GSZ   128
#define NC    (NA*5)            // 15
#define NPRED (NA*GSZ*GSZ)      // 49152 preds per image
#define NTOT  (NB*NPRED)        // 393216
#define MGT   64                // gt rows
#define NWRD  (NPRED/32)        // 1536 mask words per image
#define NEGV  (-1e9f)
#define EPSV  (1e-16f)
#define NCHD  (NPRED/256)       // 192 decode chunks per image
#define RSEG  96                // reduce segments per image (512 preds each)
#define RBLK  (NB*RSEG)         // 768 reduce blocks

#define LOG2E 1.442695040888963f
#define LN2   0.693147180559945f

// Fast transcendentals on the gfx950 special-function pipe (~1 ulp).
__device__ __forceinline__ float f_rcp(float x)  { return __builtin_amdgcn_rcpf(x); }
__device__ __forceinline__ float f_log(float x)  { return __builtin_amdgcn_logf(x) * LN2; }
__device__ __forceinline__ float f_tanh(float x) {
    float e = __builtin_amdgcn_exp2f(x * (2.0f * LOG2E));
    return 1.0f - 2.0f * f_rcp(e + 1.0f);
}
__device__ __forceinline__ float f_sigmoid(float x) {
    return f_rcp(1.0f + __builtin_amdgcn_exp2f(-x * LOG2E));
}

// GIoU/IoU exactly mirroring the reference arithmetic order (fp32).
__device__ __forceinline__ void gou_iou(const float4 p, const float4 g,
                                        float& iou, float& gou) {
    float px1 = p.x - p.z * 0.5f, px2 = p.x + p.z * 0.5f;
    float py1 = p.y - p.w * 0.5f, py2 = p.y + p.w * 0.5f;
    float gx1 = g.x - g.z * 0.5f, gx2 = g.x + g.z * 0.5f;
    float gy1 = g.y - g.w * 0.5f, gy2 = g.y + g.w * 0.5f;
    float iw = fmaxf(fminf(px2, gx2) - fmaxf(px1, gx1), 0.0f);
    float ih = fmaxf(fminf(py2, gy2) - fmaxf(py1, gy1), 0.0f);
    float inter = iw * ih;
    float ap = (px2 - px1) * (py2 - py1);
    float ag = (gx2 - gx1) * (gy2 - gy1);
    float un = ap + ag - inter;
    iou = inter / (un + EPSV);
    float cw = fmaxf(px2, gx2) - fminf(px1, gx1);
    float ch = fmaxf(py2, gy2) - fminf(py1, gy1);
    float ac = cw * ch;
    gou = iou - (ac - un) / (ac + EPSV);
}

// K1: decode preds -> pd/conf AND fused round-1 argmax partials.
// Each block owns 256 contiguous preds of one image; the decoded pred stays
// in registers for the per-gt GIoU scan (no pd re-read). Partials are exact
// first-occurrence argmaxes over the block's 256-pred chunk.
__global__ __launch_bounds__(256) void k_decode(const float* __restrict__ out,
                                                const float* __restrict__ gts,
                                                float4* __restrict__ pd,
                                                float* __restrict__ conf,
                                                float* __restrict__ pval,
                                                int* __restrict__ ppd,
                                                unsigned* __restrict__ done) {
    const int tid = threadIdx.x;
    const int b = blockIdx.x / NCHD;          // image
    const int ch = blockIdx.x % NCHD;         // chunk within image
    __shared__ float4 gbA[MGT];
    __shared__ int glist[MGT];
    __shared__ int ng_s;
    __shared__ float lv[4][MGT];
    __shared__ int lp[4][MGT];

    if (blockIdx.x == 0 && tid == 0) *done = 0u;   // ticket for k_reduce
    if (tid < MGT) {
        gbA[tid] = make_float4(gts[tid * 5 + 1], gts[tid * 5 + 2],
                               gts[tid * 5 + 3], gts[tid * 5 + 4]);
    }
    __syncthreads();
    if (tid == 0) {
        int c = 0;
        for (int j = 0; j < MGT; j++)
            if (gts[j * 5] == (float)b) glist[c++] = j;   // ascending j
        ng_s = c;
    }
    __syncthreads();

    // decode
    const int idx = blockIdx.x * 256 + tid;
    const int p_loc = ch * 256 + tid;         // pred index within image
    int a = p_loc / (GSZ * GSZ), r = p_loc % (GSZ * GSZ);
    int y = r / GSZ, x = r % GSZ;
    const float* base = out + ((((size_t)b * NC + a * 5) * GSZ + y) * GSZ + x);
    const int st = GSZ * GSZ;
    float t0 = base[0], t1 = base[st], t2 = base[2 * st], t3 = base[3 * st], t4 = base[4 * st];
    const float inv_gs = 1.0f / (float)GSZ;   // exact (pow2)
    float4 P;
    P.x = (f_tanh(t0) + 0.5f + (float)x) * inv_gs;
    P.y = (f_tanh(t1) + 0.5f + (float)y) * inv_gs;
    P.z = __builtin_amdgcn_exp2f(-(t2 * t2) * LOG2E);
    P.w = __builtin_amdgcn_exp2f(-(t3 * t3) * LOG2E);
    pd[idx] = P;
    conf[idx] = f_sigmoid(t4);

    // fused per-gt argmax over this chunk (pred lives in registers)
    const int ng = ng_s;
    for (int m = 0; m < ng; m++) {
        float4 g = gbA[glist[m]];
        float iu, go; gou_iou(P, g, iu, go);
        float bv = go; int bp = tid;
        for (int off = 32; off > 0; off >>= 1) {
            float v2 = __shfl_down(bv, off, 64);
            int   p2 = __shfl_down(bp, off, 64);
            if (v2 > bv || (v2 == bv && p2 < bp)) { bv = v2; bp = p2; }
        }
        if ((tid & 63) == 0) { lv[tid >> 6][m] = bv; lp[tid >> 6][m] = bp; }
    }
    __syncthreads();
    if (tid < ng) {
        float fv = lv[0][tid]; int fp = lp[0][tid];
        for (int w = 1; w < 4; w++)
            if (lv[w][tid] > fv || (lv[w][tid] == fv && lp[w][tid] < fp)) {
                fv = lv[w][tid]; fp = lp[w][tid];
            }
        int j = glist[tid];
        pval[j * NCHD + ch] = fv;
        ppd[j * NCHD + ch]  = ch * 256 + fp;  // pred index within image
    }
}

// K2: greedy matching, one workgroup per image; merges k_decode's chunk
// partials to seed the per-gt argmax cache. Replicates the reference
// while_loop exactly (first-occurrence argmax ties, winner scatter-max,
// first-j Amat selection).
#define MTH 1024
__global__ __launch_bounds__(MTH) void k_match(const float* __restrict__ gts,
                                               const float* __restrict__ pval,
                                               const int* __restrict__ ppd,
                                               const float4* __restrict__ pd,
                                               unsigned* __restrict__ tpbits_g,
                                               int* __restrict__ pidx_g) {
    const int b = blockIdx.x;
    const int tid = threadIdx.x;
    __shared__ unsigned mbits[NWRD];            // matched-pred bitmask
    __shared__ float4 gb[MGT];
    __shared__ int gvalid[MGT], sel[MGT], pdj[MGT], cpd[MGT], cok[MGT];
    __shared__ float valj[MGT], cval[MGT];
    __shared__ float rv[MTH];
    __shared__ int rp[MTH];
    __shared__ int cont;

    for (int i = tid; i < NWRD; i += MTH) mbits[i] = 0u;
    if (tid < MGT) {
        int v = (gts[tid * 5] == (float)b) ? 1 : 0;
        gvalid[tid] = v;
        gb[tid] = make_float4(gts[tid * 5 + 1], gts[tid * 5 + 2],
                              gts[tid * 5 + 3], gts[tid * 5 + 4]);
        sel[tid] = 0;
        cok[tid] = v;                           // round-1 argmax pre-seeded
        float fv = NEGV; int fp = 0;
        if (v) {
            // ascending chunk = ascending p: strict > keeps first occurrence
            for (int ch = 0; ch < NCHD; ch++) {
                float v2 = pval[tid * NCHD + ch];
                int   p2 = ppd[tid * NCHD + ch];
                if (v2 > fv || (v2 == fv && p2 < fp)) { fv = v2; fp = p2; }
            }
        }
        cval[tid] = fv; cpd[tid] = fp;
        valj[tid] = NEGV; pdj[tid] = 0;
    }
    __syncthreads();

    const float4* pdb = pd + (size_t)b * NPRED;
    for (int it = 0; it < MGT + 2; ++it) {
        __syncthreads();
        if (tid == 0) {
            int c = 0;
            for (int j = 0; j < MGT; j++) if (gvalid[j] && !sel[j]) { c = 1; break; }
            cont = c;
        }
        __syncthreads();
        if (!cont) break;

        // step 1: per active gt, argmax over unmatched preds of gou(p,j).
        // If gt j's cached best pred is still unmatched, the argmax is
        // unchanged (mask only grows) -> skip the rescan.
        for (int j = 0; j < MGT; j++) {
            bool active = gvalid[j] && !sel[j];          // uniform across block
            if (!active) {
                if (tid == 0) { valj[j] = NEGV; pdj[j] = 0; }
                continue;
            }
            if (cok[j]) {
                int pp = cpd[j];
                if (!((mbits[pp >> 5] >> (pp & 31)) & 1u)) {
                    if (tid == 0) { valj[j] = cval[j]; pdj[j] = pp; }
                    continue;
                }
            }
            float4 g = gb[j];
            float bv = NEGV; int bp = 0x7FFFFFFF;
            for (int p = tid; p < NPRED; p += MTH) {
                if ((mbits[p >> 5] >> (p & 31)) & 1u) continue;
                float iu, go; gou_iou(pdb[p], g, iu, go);
                if (go > bv) { bv = go; bp = p; }        // strict > : first max
            }
            rv[tid] = bv; rp[tid] = bp;
            __syncthreads();
            for (int s = MTH / 2; s > 0; s >>= 1) {
                if (tid < s) {
                    float v2 = rv[tid + s]; int p2 = rp[tid + s];
                    if (v2 > rv[tid] || (v2 == rv[tid] && p2 < rp[tid])) {
                        rv[tid] = v2; rp[tid] = p2;
                    }
                }
                __syncthreads();
            }
            if (tid == 0) {
                cval[j] = rv[0]; cpd[j] = rp[0]; cok[j] = 1;
                valj[j] = rv[0]; pdj[j] = rp[0];
            }
            __syncthreads();
        }
        __syncthreads();

        // step 2: conflict resolution (threads 0..63, one per gt).
        if (tid < MGT) {
            int jj = tid;
            if (gvalid[jj] && !sel[jj]) {
                int p = pdj[jj];
                float myv = valj[jj];
                float w = NEGV;
                for (int j2 = 0; j2 < MGT; j2++)
                    if (pdj[j2] == p) w = fmaxf(w, valj[j2]);   // winner[p]
                bool win = (myv >= w) && (w > NEGV * 0.5f);
                if (win) {
                    for (int j2 = 0; j2 < jj; j2++)
                        if (pdj[j2] == p && valj[j2] >= w) { win = false; break; }
                }
                if (win) {
                    atomicOr(&mbits[p >> 5], 1u << (p & 31));
                    sel[jj] = 1;
                    pidx_g[(size_t)b * NPRED + p] = jj;
                }
            }
        }
    }
    __syncthreads();
    for (int i = tid; i < NWRD; i += MTH) tpbits_g[b * NWRD + i] = mbits[i];
}

// K3: fallback argmax + loss partial sums (fp64) + last-block finalize.
// Each block covers 512 contiguous preds of one image and builds the
// valid-gt list locally. Finalize via ticket (__threadfence + device atomic).
__global__ __launch_bounds__(256) void k_reduce(const float* __restrict__ gts,
                                                const float4* __restrict__ pd,
                                                const float* __restrict__ conf,
                                                const unsigned* __restrict__ tpbits,
                                                const int* __restrict__ pidx,
                                                double* __restrict__ partial,
                                                unsigned* __restrict__ done,
                                                float* __restrict__ o) {
    __shared__ float4 gb[MGT];
    __shared__ int vl_s[MGT];
    __shared__ int ng_s;
    __shared__ double wsum[4][9];
    __shared__ int isLast;
    const int tid = threadIdx.x;
    const int b = blockIdx.x / RSEG;
    const int seg = blockIdx.x % RSEG;
    if (tid < MGT) {
        gb[tid] = make_float4(gts[tid * 5 + 1], gts[tid * 5 + 2],
                              gts[tid * 5 + 3], gts[tid * 5 + 4]);
    }
    __syncthreads();
    if (tid == 0) {
        int c = 0;
        for (int j = 0; j < MGT; j++)
            if (gts[j * 5] == (float)b) vl_s[c++] = j;   // ascending j
        ng_s = c;
    }
    __syncthreads();
    const int ng = ng_s;
    // s: 0 cnt, 1 sxy, 2 swh, 3 sgou, 4 siou, 5 icnt, 6 sbce, 7 sinter, 8 sarea
    double s[9] = {0, 0, 0, 0, 0, 0, 0, 0, 0};
    for (int it = 0; it < 2; ++it) {
        int p = seg * 512 + it * 256 + tid;              // pred within image
        int idx = b * NPRED + p;
        int tp = (tpbits[b * NWRD + (p >> 5)] >> (p & 31)) & 1;
        float4 P = pd[idx];
        float pg = 0.0f, pi = 0.0f;
        int j = 0;
        if (ng > 0) {
            if (tp) {
                j = pidx[idx];
                gou_iou(P, gb[j], pi, pg);
            } else {
                float best = NEGV, besti = 0.0f;
                for (int m = 0; m < ng; m++) {
                    int jj = vl_s[m];                    // ascending j
                    float iu, go; gou_iou(P, gb[jj], iu, go);
                    if (go > best) { best = go; besti = iu; j = jj; }  // first max
                }
                pg = best; pi = besti;
            }
        }
        bool thr = pi > 0.5f;
        bool ig = (!thr) || tp;
        float c = conf[idx];
        c = fminf(fmaxf(c, 1e-7f), 1.0f - 1e-7f);
        if (tp) {
            s[0] += 1.0;
            float dx = P.x - gb[j].x, dy = P.y - gb[j].y;
            s[1] += (double)(dx * dx) + (double)(dy * dy);
            float lw = f_log(P.z) - f_log(gb[j].z);
            float lh = f_log(P.w) - f_log(gb[j].w);
            s[2] += (double)(lw * lw) + (double)(lh * lh);
            s[3] += (double)pg;
            s[4] += (double)pi;
        }
        if (ig) {
            s[5] += 1.0;
            float bce = tp ? -f_log(c) : -f_log(1.0f - c);
            s[6] += (double)bce;
            if (tp) s[7] += (double)c;
            s[8] += (double)c * (double)c;
        }
    }
    // wave-64 shuffle reduce, then cross-wave via LDS, one row per block
    for (int k = 0; k < 9; k++) {
        double v = s[k];
        for (int off = 32; off > 0; off >>= 1) v += __shfl_down(v, off, 64);
        s[k] = v;
    }
    if ((tid & 63) == 0)
        for (int k = 0; k < 9; k++) wsum[tid >> 6][k] = s[k];
    __syncthreads();
    if (tid < 9)
        partial[blockIdx.x * 9 + tid] =
            wsum[0][tid] + wsum[1][tid] + wsum[2][tid] + wsum[3][tid];
    __syncthreads();
    if (tid == 0) {
        __threadfence();                                  // release partials
        unsigned old = atomicAdd(done, 1u);               // device-scope ticket
        isLast = (old == RBLK - 1) ? 1 : 0;
    }
    __syncthreads();
    if (!isLast) return;
    __threadfence();                                      // acquire partials

    double t[9] = {0, 0, 0, 0, 0, 0, 0, 0, 0};
    for (int bb = tid; bb < RBLK; bb += 256)
        for (int k = 0; k < 9; k++) t[k] += partial[bb * 9 + k];
    for (int k = 0; k < 9; k++) {
        double v = t[k];
        for (int off = 32; off > 0; off >>= 1) v += __shfl_down(v, off, 64);
        t[k] = v;
    }
    if ((tid & 63) == 0)
        for (int k = 0; k < 9; k++) wsum[tid >> 6][k] = t[k];
    __syncthreads();
    if (tid == 0) {
        double acc[9];
        for (int k = 0; k < 9; k++)
            acc[k] = wsum[0][k] + wsum[1][k] + wsum[2][k] + wsum[3][k];
        double cnt_raw = acc[0];
        double cnt = cnt_raw > 1.0 ? cnt_raw : 1.0;
        double lxy  = acc[1] / cnt;
        double lwh  = acc[2] / cnt;
        double lgou = 1.0 - acc[3] / cnt;
        double liou = 1.0 - acc[4] / cnt;
        double icnt = acc[5] > 1.0 ? acc[5] : 1.0;
        double lbce = acc[6] / icnt;
        // gt_area = (tpf*ig).sum() == raw tp count (ig superset of tp), UNclamped
        double ldice = 1.0 - (2.0 * acc[7] + 1.0) / (acc[8] + cnt_raw + 1.0);
        double lconf = ldice + lbce;
        double tot = lconf + 2.0 * lgou + lwh + lxy;
        o[0] = (float)lxy;
        o[1] = (float)lwh;
        o[2] = (float)lconf;
        o[3] = (float)liou;
        o[4] = (float)lgou;
        o[5] = (float)tot;
    }
}

extern "C" void kernel_launch(void* const* d_in, const int* in_sizes, int n_in,
                              void* d_out, int out_size, void* d_ws, size_t ws_size,
                              hipStream_t stream) {
    const float* out_t = (const float*)d_in[0];  // [8,15,128,128]
    const float* gts   = (const float*)d_in[1];  // [64,5]
    char* ws = (char*)d_ws;
    size_t off = 0;
    unsigned* done    = (unsigned*)(ws + off);  off += 256;
    double*   partial = (double*)(ws + off);    off += (size_t)RBLK * 9 * 8;    // 55296
    float*    pval    = (float*)(ws + off);     off += (size_t)MGT * NCHD * 4;  // 49152
    int*      ppd     = (int*)(ws + off);       off += (size_t)MGT * NCHD * 4;  // 49152
    unsigned* tpbits  = (unsigned*)(ws + off);  off += (size_t)NB * NWRD * 4;   // 49152
    int*      pidx    = (int*)(ws + off);       off += (size_t)NTOT * 4;        // 1.5 MB
    off = (off + 15) & ~(size_t)15;
    float4*   pd      = (float4*)(ws + off);    off += (size_t)NTOT * 16;       // 6.3 MB
    float*    conf    = (float*)(ws + off);     off += (size_t)NTOT * 4;        // 1.5 MB
    float* o = (float*)d_out;

    k_decode<<<NTOT / 256, 256, 0, stream>>>(out_t, gts, pd, conf, pval, ppd, done);
    k_match <<<NB, MTH, 0, stream>>>(gts, pval, ppd, pd, tpbits, pidx);
    k_reduce<<<RBLK, 256, 0, stream>>>(gts, pd, conf, tpbits, pidx, partial, done, o);
}

// Round 6
// 111.595 us; speedup vs baseline: 1.3449x; 1.3449x over previous
//
#include <hip/hip_runtime.h>

// Problem constants (fixed by reference setup_inputs):
#define NB    8
#define NA    3
#define GSZ   128
#define NC    (NA*5)            // 15
#define NPRED (NA*GSZ*GSZ)      // 49152 preds per image
#define NTOT  (NB*NPRED)        // 393216
#define MGT   64                // gt rows
#define NWRD  (NPRED/32)        // 1536 mask words per image
#define NEGV  (-1e9f)
#define EPSV  (1e-16f)
#define NCHD  (NPRED/256)       // 192 decode chunks per image
#define RSEG  96                // reduce segments per image (512 preds each)
#define RBLK  (NB*RSEG)         // 768 reduce blocks

#define LOG2E 1.442695040888963f
#define LN2   0.693147180559945f

// Fast transcendentals on the gfx950 special-function pipe (~1 ulp).
__device__ __forceinline__ float f_rcp(float x)  { return __builtin_amdgcn_rcpf(x); }
__device__ __forceinline__ float f_log(float x)  { return __builtin_amdgcn_logf(x) * LN2; }
__device__ __forceinline__ float f_tanh(float x) {
    float e = __builtin_amdgcn_exp2f(x * (2.0f * LOG2E));
    return 1.0f - 2.0f * f_rcp(e + 1.0f);
}
__device__ __forceinline__ float f_sigmoid(float x) {
    return f_rcp(1.0f + __builtin_amdgcn_exp2f(-x * LOG2E));
}

// GIoU/IoU exactly mirroring the reference arithmetic order (fp32).
__device__ __forceinline__ void gou_iou(const float4 p, const float4 g,
                                        float& iou, float& gou) {
    float px1 = p.x - p.z * 0.5f, px2 = p.x + p.z * 0.5f;
    float py1 = p.y - p.w * 0.5f, py2 = p.y + p.w * 0.5f;
    float gx1 = g.x - g.z * 0.5f, gx2 = g.x + g.z * 0.5f;
    float gy1 = g.y - g.w * 0.5f, gy2 = g.y + g.w * 0.5f;
    float iw = fmaxf(fminf(px2, gx2) - fmaxf(px1, gx1), 0.0f);
    float ih = fmaxf(fminf(py2, gy2) - fmaxf(py1, gy1), 0.0f);
    float inter = iw * ih;
    float ap = (px2 - px1) * (py2 - py1);
    float ag = (gx2 - gx1) * (gy2 - gy1);
    float un = ap + ag - inter;
    iou = inter / (un + EPSV);
    float cw = fmaxf(px2, gx2) - fminf(px1, gx1);
    float ch = fmaxf(py2, gy2) - fminf(py1, gy1);
    float ac = cw * ch;
    gou = iou - (ac - un) / (ac + EPSV);
}

// K1: decode preds -> pd/conf AND fused round-1 argmax chunk partials.
// Valid-gt list built via ballot (no serial tid0 loop).
__global__ __launch_bounds__(256) void k_decode(const float* __restrict__ out,
                                                const float* __restrict__ gts,
                                                float4* __restrict__ pd,
                                                float* __restrict__ conf,
                                                float* __restrict__ pval,
                                                int* __restrict__ ppd,
                                                unsigned* __restrict__ done) {
    const int tid = threadIdx.x;
    const int b = blockIdx.x / NCHD;          // image
    const int ch = blockIdx.x % NCHD;         // chunk within image
    __shared__ float4 gbA[MGT];
    __shared__ int glist[MGT];
    __shared__ int ng_s;
    __shared__ float lv[4][MGT];
    __shared__ int lp[4][MGT];

    if (blockIdx.x == 0 && tid == 0) *done = 0u;   // ticket for k_reduce
    if (tid < MGT) {
        gbA[tid] = make_float4(gts[tid * 5 + 1], gts[tid * 5 + 2],
                               gts[tid * 5 + 3], gts[tid * 5 + 4]);
        bool v = (gts[tid * 5] == (float)b);
        unsigned long long m = __ballot(v);
        if (v) glist[(int)__popcll(m & ((1ull << tid) - 1ull))] = tid;  // ascending j
        if (tid == 0) ng_s = (int)__popcll(m);
    }
    __syncthreads();

    // decode
    const int idx = blockIdx.x * 256 + tid;
    const int p_loc = ch * 256 + tid;         // pred index within image
    int a = p_loc / (GSZ * GSZ), r = p_loc % (GSZ * GSZ);
    int y = r / GSZ, x = r % GSZ;
    const float* base = out + ((((size_t)b * NC + a * 5) * GSZ + y) * GSZ + x);
    const int st = GSZ * GSZ;
    float t0 = base[0], t1 = base[st], t2 = base[2 * st], t3 = base[3 * st], t4 = base[4 * st];
    const float inv_gs = 1.0f / (float)GSZ;   // exact (pow2)
    float4 P;
    P.x = (f_tanh(t0) + 0.5f + (float)x) * inv_gs;
    P.y = (f_tanh(t1) + 0.5f + (float)y) * inv_gs;
    P.z = __builtin_amdgcn_exp2f(-(t2 * t2) * LOG2E);
    P.w = __builtin_amdgcn_exp2f(-(t3 * t3) * LOG2E);
    pd[idx] = P;
    conf[idx] = f_sigmoid(t4);

    // fused per-gt argmax over this 256-pred chunk (pred lives in registers)
    const int ng = ng_s;
    for (int m = 0; m < ng; m++) {
        float4 g = gbA[glist[m]];
        float iu, go; gou_iou(P, g, iu, go);
        float bv = go; int bp = tid;
        for (int off = 32; off > 0; off >>= 1) {
            float v2 = __shfl_down(bv, off, 64);
            int   p2 = __shfl_down(bp, off, 64);
            if (v2 > bv || (v2 == bv && p2 < bp)) { bv = v2; bp = p2; }
        }
        if ((tid & 63) == 0) { lv[tid >> 6][m] = bv; lp[tid >> 6][m] = bp; }
    }
    __syncthreads();
    if (tid < ng) {
        float fv = lv[0][tid]; int fp = lp[0][tid];
        for (int w = 1; w < 4; w++)
            if (lv[w][tid] > fv || (lv[w][tid] == fv && lp[w][tid] < fp)) {
                fv = lv[w][tid]; fp = lp[w][tid];
            }
        int j = glist[tid];
        pval[j * NCHD + ch] = fv;
        ppd[j * NCHD + ch]  = ch * 256 + fp;  // pred index within image
    }
}

// K2: greedy matching, one workgroup per image. Per-gt state in WAVE-0
// REGISTERS (lane j = gt j); rounds are ballot+shuffle (no LDS latency
// chains); block-wide rescans only for stolen cached argmaxes.
// Replicates the reference while_loop exactly (first-occurrence argmax
// ties, winner scatter-max, first-j Amat selection).
#define MTH 1024
__global__ __launch_bounds__(MTH) void k_match(const float* __restrict__ gts,
                                               const float* __restrict__ pval,
                                               const int* __restrict__ ppd,
                                               const float4* __restrict__ pd,
                                               unsigned* __restrict__ tpbits_g,
                                               int* __restrict__ pidx_g) {
    const int b = blockIdx.x;
    const int tid = threadIdx.x;
    __shared__ unsigned mbits[NWRD];            // matched-pred bitmask
    __shared__ float4 gb[MGT];
    __shared__ float sh_v[MGT];
    __shared__ int   sh_p[MGT];
    __shared__ float sh_rv[16];
    __shared__ int   sh_rp[16];
    __shared__ unsigned long long sh_need;
    __shared__ int sh_cont;

    for (int i = tid; i < NWRD; i += MTH) mbits[i] = 0u;
    if (tid < MGT)
        gb[tid] = make_float4(gts[tid * 5 + 1], gts[tid * 5 + 2],
                              gts[tid * 5 + 3], gts[tid * 5 + 4]);

    // parallel merge of decode's 192 chunk partials -> per-gt seed.
    // 16 threads per gt, 12 chunks each (ascending chunk = ascending pred:
    // strict > + idx-asc tiebreak == exact first-occurrence argmax).
    {
        int jt = tid >> 4, sub = tid & 15;
        float mv = NEGV; int mp = 0x7FFFFFFF;
        #pragma unroll
        for (int k = 0; k < NCHD / 16; k++) {
            int ch = sub * (NCHD / 16) + k;
            float v2 = pval[jt * NCHD + ch];
            int   p2 = ppd [jt * NCHD + ch];
            if (v2 > mv || (v2 == mv && p2 < mp)) { mv = v2; mp = p2; }
        }
        for (int off = 1; off < 16; off <<= 1) {          // xor-butterfly in 16-group
            float v2 = __shfl_xor(mv, off, 64);
            int   p2 = __shfl_xor(mp, off, 64);
            if (v2 > mv || (v2 == mv && p2 < mp)) { mv = v2; mp = p2; }
        }
        if (sub == 0) { sh_v[jt] = mv; sh_p[jt] = mp; }
    }
    __syncthreads();

    // wave-0 per-gt register state
    bool r_valid = false, r_sel = false;
    float r_cval = NEGV; int r_cpd = 0;
    if (tid < 64) {
        r_valid = (gts[tid * 5] == (float)b);
        r_cval = sh_v[tid];
        r_cpd  = sh_p[tid];
    }
    const float4* pdb = pd + (size_t)b * NPRED;

    for (int round = 0; round < MGT + 2; ++round) {
        if (tid < 64) {
            bool active = r_valid && !r_sel;
            unsigned long long am = __ballot(active);
            bool stolen = active && ((mbits[r_cpd >> 5] >> (r_cpd & 31)) & 1u);
            unsigned long long nm = __ballot(stolen);
            if (tid == 0) { sh_cont = (am != 0ull) ? 1 : 0; sh_need = nm; }
        }
        __syncthreads();
        if (!sh_cont) break;
        unsigned long long need = sh_need;

        // rescans: only gts whose cached best pred got stolen (mask only
        // grows, so an un-stolen cached argmax is still exact).
        while (need) {
            int j = __ffsll((long long)need) - 1; need &= need - 1ull;
            float4 g = gb[j];
            float bv = NEGV; int bp = 0x7FFFFFFF;
            for (int p = tid; p < NPRED; p += MTH) {
                if ((mbits[p >> 5] >> (p & 31)) & 1u) continue;
                float iu, go; gou_iou(pdb[p], g, iu, go);
                if (go > bv) { bv = go; bp = p; }        // strict > : first max
            }
            for (int off = 32; off > 0; off >>= 1) {
                float v2 = __shfl_down(bv, off, 64);
                int   p2 = __shfl_down(bp, off, 64);
                if (v2 > bv || (v2 == bv && p2 < bp)) { bv = v2; bp = p2; }
            }
            if ((tid & 63) == 0) { sh_rv[tid >> 6] = bv; sh_rp[tid >> 6] = bp; }
            __syncthreads();
            if (tid < 64) {
                float v = (tid < 16) ? sh_rv[tid] : NEGV;
                int   p = (tid < 16) ? sh_rp[tid] : 0x7FFFFFFF;
                for (int off = 1; off < 16; off <<= 1) {
                    float v2 = __shfl_xor(v, off, 64);
                    int   p2 = __shfl_xor(p, off, 64);
                    if (v2 > v || (v2 == v && p2 < p)) { v = v2; p = p2; }
                }
                v = __shfl(v, 0, 64); p = __shfl(p, 0, 64);
                if (tid == j) { r_cval = v; r_cpd = p; }
            }
            __syncthreads();
        }

        // conflict resolution, all in wave-0 registers + shuffles.
        if (tid < 64) {
            bool active = r_valid && !r_sel;
            float valj = active ? r_cval : NEGV;     // reference: inactive -> NEG
            int   pdj  = active ? r_cpd  : 0;        // reference: argmax of all-NEG = 0
            // winner[p] = scatter-max of valj over gts with pdj==p
            float w = NEGV;
            for (int j2 = 0; j2 < 64; j2++) {
                float v2 = __shfl(valj, j2, 64);
                int   p2 = __shfl(pdj,  j2, 64);
                if (p2 == pdj) w = fmaxf(w, v2);
            }
            // Amat first-j: first j2 with pdj2==p && valj2>=w
            unsigned long long fm = 0ull;
            for (int j2 = 0; j2 < 64; j2++) {
                float v2 = __shfl(valj, j2, 64);
                int   p2 = __shfl(pdj,  j2, 64);
                if (p2 == pdj && v2 >= w) fm |= (1ull << j2);
            }
            bool win = active && (w > NEGV * 0.5f) && fm &&
                       ((__ffsll((long long)fm) - 1) == tid);
            if (win) {
                r_sel = true;
                atomicOr(&mbits[pdj >> 5], 1u << (pdj & 31));
                pidx_g[(size_t)b * NPRED + pdj] = tid;
            }
        }
        __syncthreads();   // mbits visible to all before next round / rescan
    }
    __syncthreads();
    for (int i = tid; i < NWRD; i += MTH) tpbits_g[b * NWRD + i] = mbits[i];
}

// K3: fallback argmax + loss partial sums (fp64) + last-block finalize
// (ticket: __threadfence + device-scope atomic). Valid-gt list via ballot.
__global__ __launch_bounds__(256) void k_reduce(const float* __restrict__ gts,
                                                const float4* __restrict__ pd,
                                                const float* __restrict__ conf,
                                                const unsigned* __restrict__ tpbits,
                                                const int* __restrict__ pidx,
                                                double* __restrict__ partial,
                                                unsigned* __restrict__ done,
                                                float* __restrict__ o) {
    __shared__ float4 gb[MGT];
    __shared__ int vl_s[MGT];
    __shared__ int ng_s;
    __shared__ double wsum[4][9];
    __shared__ int isLast;
    const int tid = threadIdx.x;
    const int b = blockIdx.x / RSEG;
    const int seg = blockIdx.x % RSEG;
    if (tid < MGT) {
        gb[tid] = make_float4(gts[tid * 5 + 1], gts[tid * 5 + 2],
                              gts[tid * 5 + 3], gts[tid * 5 + 4]);
        bool v = (gts[tid * 5] == (float)b);
        unsigned long long m = __ballot(v);
        if (v) vl_s[(int)__popcll(m & ((1ull << tid) - 1ull))] = tid;  // ascending j
        if (tid == 0) ng_s = (int)__popcll(m);
    }
    __syncthreads();
    const int ng = ng_s;
    // s: 0 cnt, 1 sxy, 2 swh, 3 sgou, 4 siou, 5 icnt, 6 sbce, 7 sinter, 8 sarea
    double s[9] = {0, 0, 0, 0, 0, 0, 0, 0, 0};
    for (int it = 0; it < 2; ++it) {
        int p = seg * 512 + it * 256 + tid;              // pred within image
        int idx = b * NPRED + p;
        int tp = (tpbits[b * NWRD + (p >> 5)] >> (p & 31)) & 1;
        float4 P = pd[idx];
        float pg = 0.0f, pi = 0.0f;
        int j = 0;
        if (ng > 0) {
            if (tp) {
                j = pidx[idx];
                gou_iou(P, gb[j], pi, pg);
            } else {
                float best = NEGV, besti = 0.0f;
                for (int m = 0; m < ng; m++) {
                    int jj = vl_s[m];                    // ascending j
                    float iu, go; gou_iou(P, gb[jj], iu, go);
                    if (go > best) { best = go; besti = iu; j = jj; }  // first max
                }
                pg = best; pi = besti;
            }
        }
        bool thr = pi > 0.5f;
        bool ig = (!thr) || tp;
        float c = conf[idx];
        c = fminf(fmaxf(c, 1e-7f), 1.0f - 1e-7f);
        if (tp) {
            s[0] += 1.0;
            float dx = P.x - gb[j].x, dy = P.y - gb[j].y;
            s[1] += (double)(dx * dx) + (double)(dy * dy);
            float lw = f_log(P.z) - f_log(gb[j].z);
            float lh = f_log(P.w) - f_log(gb[j].w);
            s[2] += (double)(lw * lw) + (double)(lh * lh);
            s[3] += (double)pg;
            s[4] += (double)pi;
        }
        if (ig) {
            s[5] += 1.0;
            float bce = tp ? -f_log(c) : -f_log(1.0f - c);
            s[6] += (double)bce;
            if (tp) s[7] += (double)c;
            s[8] += (double)c * (double)c;
        }
    }
    for (int k = 0; k < 9; k++) {
        double v = s[k];
        for (int off = 32; off > 0; off >>= 1) v += __shfl_down(v, off, 64);
        s[k] = v;
    }
    if ((tid & 63) == 0)
        for (int k = 0; k < 9; k++) wsum[tid >> 6][k] = s[k];
    __syncthreads();
    if (tid < 9)
        partial[blockIdx.x * 9 + tid] =
            wsum[0][tid] + wsum[1][tid] + wsum[2][tid] + wsum[3][tid];
    __syncthreads();
    if (tid == 0) {
        __threadfence();                                  // release partials
        unsigned old = atomicAdd(done, 1u);               // device-scope ticket
        isLast = (old == RBLK - 1) ? 1 : 0;
    }
    __syncthreads();
    if (!isLast) return;
    __threadfence();                                      // acquire partials

    double t[9] = {0, 0, 0, 0, 0, 0, 0, 0, 0};
    for (int bb = tid; bb < RBLK; bb += 256)
        for (int k = 0; k < 9; k++) t[k] += partial[bb * 9 + k];
    for (int k = 0; k < 9; k++) {
        double v = t[k];
        for (int off = 32; off > 0; off >>= 1) v += __shfl_down(v, off, 64);
        t[k] = v;
    }
    if ((tid & 63) == 0)
        for (int k = 0; k < 9; k++) wsum[tid >> 6][k] = t[k];
    __syncthreads();
    if (tid == 0) {
        double acc[9];
        for (int k = 0; k < 9; k++)
            acc[k] = wsum[0][k] + wsum[1][k] + wsum[2][k] + wsum[3][k];
        double cnt_raw = acc[0];
        double cnt = cnt_raw > 1.0 ? cnt_raw : 1.0;
        double lxy  = acc[1] / cnt;
        double lwh  = acc[2] / cnt;
        double lgou = 1.0 - acc[3] / cnt;
        double liou = 1.0 - acc[4] / cnt;
        double icnt = acc[5] > 1.0 ? acc[5] : 1.0;
        double lbce = acc[6] / icnt;
        // gt_area = (tpf*ig).sum() == raw tp count (ig superset of tp), UNclamped
        double ldice = 1.0 - (2.0 * acc[7] + 1.0) / (acc[8] + cnt_raw + 1.0);
        double lconf = ldice + lbce;
        double tot = lconf + 2.0 * lgou + lwh + lxy;
        o[0] = (float)lxy;
        o[1] = (float)lwh;
        o[2] = (float)lconf;
        o[3] = (float)liou;
        o[4] = (float)lgou;
        o[5] = (float)tot;
    }
}

extern "C" void kernel_launch(void* const* d_in, const int* in_sizes, int n_in,
                              void* d_out, int out_size, void* d_ws, size_t ws_size,
                              hipStream_t stream) {
    const float* out_t = (const float*)d_in[0];  // [8,15,128,128]
    const float* gts   = (const float*)d_in[1];  // [64,5]
    char* ws = (char*)d_ws;
    size_t off = 0;
    unsigned* done    = (unsigned*)(ws + off);  off += 256;
    double*   partial = (double*)(ws + off);    off += (size_t)RBLK * 9 * 8;    // 55296
    float*    pval    = (float*)(ws + off);     off += (size_t)MGT * NCHD * 4;  // 49152
    int*      ppd     = (int*)(ws + off);       off += (size_t)MGT * NCHD * 4;  // 49152
    unsigned* tpbits  = (unsigned*)(ws + off);  off += (size_t)NB * NWRD * 4;   // 49152
    int*      pidx    = (int*)(ws + off);       off += (size_t)NTOT * 4;        // 1.5 MB
    off = (off + 15) & ~(size_t)15;
    float4*   pd      = (float4*)(ws + off);    off += (size_t)NTOT * 16;       // 6.3 MB
    float*    conf    = (float*)(ws + off);     off += (size_t)NTOT * 4;        // 1.5 MB
    float* o = (float*)d_out;

    k_decode<<<NTOT / 256, 256, 0, stream>>>(out_t, gts, pd, conf, pval, ppd, done);
    k_match <<<NB, MTH, 0, stream>>>(gts, pval, ppd, pd, tpbits, pidx);
    k_reduce<<<RBLK, 256, 0, stream>>>(gts, pd, conf, tpbits, pidx, partial, done, o);
}

// Round 7
// 108.440 us; speedup vs baseline: 1.3840x; 1.0291x over previous
//
#include <hip/hip_runtime.h>

// Problem constants (fixed by reference setup_inputs):
#define NB    8
#define NA    3
#define GSZ   128
#define NC    (NA*5)            // 15
#define NPRED (NA*GSZ*GSZ)      // 49152 preds per image
#define NTOT  (NB*NPRED)        // 393216
#define MGT   64                // gt rows
#define NWRD  (NPRED/32)        // 1536 mask words per image
#define NEGV  (-1e9f)
#define EPSV  (1e-16f)
#define NCHD  (NPRED/256)       // 192 decode chunks per image
#define RSEG  32                // reduce segments per image (1536 preds each)
#define RBLK  (NB*RSEG)         // 256 reduce blocks (1/CU; 3x fewer ticket atomics)

#define LOG2E 1.442695040888963f
#define LN2   0.693147180559945f

// Fast transcendentals on the gfx950 special-function pipe (~1 ulp).
__device__ __forceinline__ float f_rcp(float x)  { return __builtin_amdgcn_rcpf(x); }
__device__ __forceinline__ float f_log(float x)  { return __builtin_amdgcn_logf(x) * LN2; }
__device__ __forceinline__ float f_tanh(float x) {
    float e = __builtin_amdgcn_exp2f(x * (2.0f * LOG2E));
    return 1.0f - 2.0f * f_rcp(e + 1.0f);
}
__device__ __forceinline__ float f_sigmoid(float x) {
    return f_rcp(1.0f + __builtin_amdgcn_exp2f(-x * LOG2E));
}

// GIoU/IoU exactly mirroring the reference arithmetic order (fp32).
__device__ __forceinline__ void gou_iou(const float4 p, const float4 g,
                                        float& iou, float& gou) {
    float px1 = p.x - p.z * 0.5f, px2 = p.x + p.z * 0.5f;
    float py1 = p.y - p.w * 0.5f, py2 = p.y + p.w * 0.5f;
    float gx1 = g.x - g.z * 0.5f, gx2 = g.x + g.z * 0.5f;
    float gy1 = g.y - g.w * 0.5f, gy2 = g.y + g.w * 0.5f;
    float iw = fmaxf(fminf(px2, gx2) - fmaxf(px1, gx1), 0.0f);
    float ih = fmaxf(fminf(py2, gy2) - fmaxf(py1, gy1), 0.0f);
    float inter = iw * ih;
    float ap = (px2 - px1) * (py2 - py1);
    float ag = (gx2 - gx1) * (gy2 - gy1);
    float un = ap + ag - inter;
    iou = inter / (un + EPSV);
    float cw = fmaxf(px2, gx2) - fminf(px1, gx1);
    float ch = fmaxf(py2, gy2) - fminf(py1, gy1);
    float ac = cw * ch;
    gou = iou - (ac - un) / (ac + EPSV);
}

// K1: decode preds -> pd/conf AND fused round-1 argmax chunk partials.
// P staged once in LDS; each WAVE owns gts round-robin (4x ds_read_b128 +
// one 12-shuffle reduce per gt instead of a per-gt block-wide shuffle tree).
__global__ __launch_bounds__(256) void k_decode(const float* __restrict__ out,
                                                const float* __restrict__ gts,
                                                float4* __restrict__ pd,
                                                float* __restrict__ conf,
                                                float* __restrict__ pval,
                                                int* __restrict__ ppd,
                                                unsigned* __restrict__ done) {
    const int tid = threadIdx.x;
    const int b = blockIdx.x / NCHD;          // image
    const int ch = blockIdx.x % NCHD;         // chunk within image
    __shared__ float4 Pl[256];                // decoded preds of this chunk
    __shared__ float4 gbA[MGT];
    __shared__ int glist[MGT];
    __shared__ int ng_s;

    if (blockIdx.x == 0 && tid == 0) *done = 0u;   // ticket for k_reduce
    if (tid < MGT) {
        gbA[tid] = make_float4(gts[tid * 5 + 1], gts[tid * 5 + 2],
                               gts[tid * 5 + 3], gts[tid * 5 + 4]);
        bool v = (gts[tid * 5] == (float)b);
        unsigned long long m = __ballot(v);
        if (v) glist[(int)__popcll(m & ((1ull << tid) - 1ull))] = tid;  // ascending j
        if (tid == 0) ng_s = (int)__popcll(m);
    }

    // decode
    const int idx = blockIdx.x * 256 + tid;
    const int p_loc = ch * 256 + tid;         // pred index within image
    int a = p_loc / (GSZ * GSZ), r = p_loc % (GSZ * GSZ);
    int y = r / GSZ, x = r % GSZ;
    const float* base = out + ((((size_t)b * NC + a * 5) * GSZ + y) * GSZ + x);
    const int st = GSZ * GSZ;
    float t0 = base[0], t1 = base[st], t2 = base[2 * st], t3 = base[3 * st], t4 = base[4 * st];
    const float inv_gs = 1.0f / (float)GSZ;   // exact (pow2)
    float4 P;
    P.x = (f_tanh(t0) + 0.5f + (float)x) * inv_gs;
    P.y = (f_tanh(t1) + 0.5f + (float)y) * inv_gs;
    P.z = __builtin_amdgcn_exp2f(-(t2 * t2) * LOG2E);
    P.w = __builtin_amdgcn_exp2f(-(t3 * t3) * LOG2E);
    pd[idx] = P;
    conf[idx] = f_sigmoid(t4);
    Pl[tid] = P;
    __syncthreads();

    // per-gt argmax over this 256-pred chunk; wave w handles gts w, w+4, ...
    // Lane l owns preds 4l..4l+3 (ascending) -> strict > keeps first max;
    // cross-lane tiebreak idx-asc -> exact first-occurrence semantics.
    const int ng = ng_s;
    const int wave = tid >> 6, lane = tid & 63;
    for (int m = wave; m < ng; m += 4) {
        float4 g = gbA[glist[m]];
        float bv = NEGV; int bp = 0;
        #pragma unroll
        for (int k = 0; k < 4; k++) {
            int p = lane * 4 + k;
            float iu, go; gou_iou(Pl[p], g, iu, go);
            if (go > bv) { bv = go; bp = p; }
        }
        for (int off = 32; off > 0; off >>= 1) {
            float v2 = __shfl_down(bv, off, 64);
            int   p2 = __shfl_down(bp, off, 64);
            if (v2 > bv || (v2 == bv && p2 < bp)) { bv = v2; bp = p2; }
        }
        if (lane == 0) {
            int j = glist[m];
            pval[j * NCHD + ch] = bv;
            ppd[j * NCHD + ch]  = ch * 256 + bp;   // pred index within image
        }
    }
}

// K2: greedy matching, one workgroup per image. Per-gt state in WAVE-0
// REGISTERS (lane j = gt j); rounds are ballot+shuffle (no LDS latency
// chains); block-wide rescans only for stolen cached argmaxes.
// Replicates the reference while_loop exactly (first-occurrence argmax
// ties, winner scatter-max, first-j Amat selection).
#define MTH 1024
__global__ __launch_bounds__(MTH) void k_match(const float* __restrict__ gts,
                                               const float* __restrict__ pval,
                                               const int* __restrict__ ppd,
                                               const float4* __restrict__ pd,
                                               unsigned* __restrict__ tpbits_g,
                                               int* __restrict__ pidx_g) {
    const int b = blockIdx.x;
    const int tid = threadIdx.x;
    __shared__ unsigned mbits[NWRD];            // matched-pred bitmask
    __shared__ float4 gb[MGT];
    __shared__ float sh_v[MGT];
    __shared__ int   sh_p[MGT];
    __shared__ float sh_rv[16];
    __shared__ int   sh_rp[16];
    __shared__ unsigned long long sh_need;
    __shared__ int sh_cont;

    for (int i = tid; i < NWRD; i += MTH) mbits[i] = 0u;
    if (tid < MGT)
        gb[tid] = make_float4(gts[tid * 5 + 1], gts[tid * 5 + 2],
                              gts[tid * 5 + 3], gts[tid * 5 + 4]);

    // parallel merge of decode's 192 chunk partials -> per-gt seed.
    // 16 threads per gt, 12 chunks each (ascending chunk = ascending pred:
    // strict > + idx-asc tiebreak == exact first-occurrence argmax).
    {
        int jt = tid >> 4, sub = tid & 15;
        float mv = NEGV; int mp = 0x7FFFFFFF;
        #pragma unroll
        for (int k = 0; k < NCHD / 16; k++) {
            int ch = sub * (NCHD / 16) + k;
            float v2 = pval[jt * NCHD + ch];
            int   p2 = ppd [jt * NCHD + ch];
            if (v2 > mv || (v2 == mv && p2 < mp)) { mv = v2; mp = p2; }
        }
        for (int off = 1; off < 16; off <<= 1) {          // xor-butterfly in 16-group
            float v2 = __shfl_xor(mv, off, 64);
            int   p2 = __shfl_xor(mp, off, 64);
            if (v2 > mv || (v2 == mv && p2 < mp)) { mv = v2; mp = p2; }
        }
        if (sub == 0) { sh_v[jt] = mv; sh_p[jt] = mp; }
    }
    __syncthreads();

    // wave-0 per-gt register state
    bool r_valid = false, r_sel = false;
    float r_cval = NEGV; int r_cpd = 0;
    if (tid < 64) {
        r_valid = (gts[tid * 5] == (float)b);
        r_cval = sh_v[tid];
        r_cpd  = sh_p[tid];
    }
    const float4* pdb = pd + (size_t)b * NPRED;

    for (int round = 0; round < MGT + 2; ++round) {
        if (tid < 64) {
            bool active = r_valid && !r_sel;
            unsigned long long am = __ballot(active);
            bool stolen = active && ((mbits[r_cpd >> 5] >> (r_cpd & 31)) & 1u);
            unsigned long long nm = __ballot(stolen);
            if (tid == 0) { sh_cont = (am != 0ull) ? 1 : 0; sh_need = nm; }
        }
        __syncthreads();
        if (!sh_cont) break;
        unsigned long long need = sh_need;

        // rescans: only gts whose cached best pred got stolen (mask only
        // grows, so an un-stolen cached argmax is still exact).
        while (need) {
            int j = __ffsll((long long)need) - 1; need &= need - 1ull;
            float4 g = gb[j];
            float bv = NEGV; int bp = 0x7FFFFFFF;
            for (int p = tid; p < NPRED; p += MTH) {
                if ((mbits[p >> 5] >> (p & 31)) & 1u) continue;
                float iu, go; gou_iou(pdb[p], g, iu, go);
                if (go > bv) { bv = go; bp = p; }        // strict > : first max
            }
            for (int off = 32; off > 0; off >>= 1) {
                float v2 = __shfl_down(bv, off, 64);
                int   p2 = __shfl_down(bp, off, 64);
                if (v2 > bv || (v2 == bv && p2 < bp)) { bv = v2; bp = p2; }
            }
            if ((tid & 63) == 0) { sh_rv[tid >> 6] = bv; sh_rp[tid >> 6] = bp; }
            __syncthreads();
            if (tid < 64) {
                float v = (tid < 16) ? sh_rv[tid] : NEGV;
                int   p = (tid < 16) ? sh_rp[tid] : 0x7FFFFFFF;
                for (int off = 1; off < 16; off <<= 1) {
                    float v2 = __shfl_xor(v, off, 64);
                    int   p2 = __shfl_xor(p, off, 64);
                    if (v2 > v || (v2 == v && p2 < p)) { v = v2; p = p2; }
                }
                v = __shfl(v, 0, 64); p = __shfl(p, 0, 64);
                if (tid == j) { r_cval = v; r_cpd = p; }
            }
            __syncthreads();
        }

        // conflict resolution, all in wave-0 registers + shuffles.
        if (tid < 64) {
            bool active = r_valid && !r_sel;
            float valj = active ? r_cval : NEGV;     // reference: inactive -> NEG
            int   pdj  = active ? r_cpd  : 0;        // reference: argmax of all-NEG = 0
            // winner[p] = scatter-max of valj over gts with pdj==p
            float w = NEGV;
            for (int j2 = 0; j2 < 64; j2++) {
                float v2 = __shfl(valj, j2, 64);
                int   p2 = __shfl(pdj,  j2, 64);
                if (p2 == pdj) w = fmaxf(w, v2);
            }
            // Amat first-j: first j2 with pdj2==p && valj2>=w
            unsigned long long fm = 0ull;
            for (int j2 = 0; j2 < 64; j2++) {
                float v2 = __shfl(valj, j2, 64);
                int   p2 = __shfl(pdj,  j2, 64);
                if (p2 == pdj && v2 >= w) fm |= (1ull << j2);
            }
            bool win = active && (w > NEGV * 0.5f) && fm &&
                       ((__ffsll((long long)fm) - 1) == tid);
            if (win) {
                r_sel = true;
                atomicOr(&mbits[pdj >> 5], 1u << (pdj & 31));
                pidx_g[(size_t)b * NPRED + pdj] = tid;
            }
        }
        __syncthreads();   // mbits visible to all before next round / rescan
    }
    __syncthreads();
    for (int i = tid; i < NWRD; i += MTH) tpbits_g[b * NWRD + i] = mbits[i];
}

// K3: fallback argmax + loss partial sums (fp64) + last-block finalize
// (ticket: __threadfence + device-scope atomic; 256 blocks -> 3x less
// ticket contention than 768). Valid-gt list via ballot.
__global__ __launch_bounds__(256) void k_reduce(const float* __restrict__ gts,
                                                const float4* __restrict__ pd,
                                                const float* __restrict__ conf,
                                                const unsigned* __restrict__ tpbits,
                                                const int* __restrict__ pidx,
                                                double* __restrict__ partial,
                                                unsigned* __restrict__ done,
                                                float* __restrict__ o) {
    __shared__ float4 gb[MGT];
    __shared__ int vl_s[MGT];
    __shared__ int ng_s;
    __shared__ double wsum[4][9];
    __shared__ int isLast;
    const int tid = threadIdx.x;
    const int b = blockIdx.x / RSEG;
    const int seg = blockIdx.x % RSEG;
    if (tid < MGT) {
        gb[tid] = make_float4(gts[tid * 5 + 1], gts[tid * 5 + 2],
                              gts[tid * 5 + 3], gts[tid * 5 + 4]);
        bool v = (gts[tid * 5] == (float)b);
        unsigned long long m = __ballot(v);
        if (v) vl_s[(int)__popcll(m & ((1ull << tid) - 1ull))] = tid;  // ascending j
        if (tid == 0) ng_s = (int)__popcll(m);
    }
    __syncthreads();
    const int ng = ng_s;
    // s: 0 cnt, 1 sxy, 2 swh, 3 sgou, 4 siou, 5 icnt, 6 sbce, 7 sinter, 8 sarea
    double s[9] = {0, 0, 0, 0, 0, 0, 0, 0, 0};
    #pragma unroll
    for (int it = 0; it < 6; ++it) {
        int p = seg * 1536 + it * 256 + tid;             // pred within image
        int idx = b * NPRED + p;
        int tp = (tpbits[b * NWRD + (p >> 5)] >> (p & 31)) & 1;
        float4 P = pd[idx];
        float pg = 0.0f, pi = 0.0f;
        int j = 0;
        if (ng > 0) {
            if (tp) {
                j = pidx[idx];
                gou_iou(P, gb[j], pi, pg);
            } else {
                float best = NEGV, besti = 0.0f;
                for (int m = 0; m < ng; m++) {
                    int jj = vl_s[m];                    // ascending j
                    float iu, go; gou_iou(P, gb[jj], iu, go);
                    if (go > best) { best = go; besti = iu; j = jj; }  // first max
                }
                pg = best; pi = besti;
            }
        }
        bool thr = pi > 0.5f;
        bool ig = (!thr) || tp;
        float c = conf[idx];
        c = fminf(fmaxf(c, 1e-7f), 1.0f - 1e-7f);
        if (tp) {
            s[0] += 1.0;
            float dx = P.x - gb[j].x, dy = P.y - gb[j].y;
            s[1] += (double)(dx * dx) + (double)(dy * dy);
            float lw = f_log(P.z) - f_log(gb[j].z);
            float lh = f_log(P.w) - f_log(gb[j].w);
            s[2] += (double)(lw * lw) + (double)(lh * lh);
            s[3] += (double)pg;
            s[4] += (double)pi;
        }
        if (ig) {
            s[5] += 1.0;
            float bce = tp ? -f_log(c) : -f_log(1.0f - c);
            s[6] += (double)bce;
            if (tp) s[7] += (double)c;
            s[8] += (double)c * (double)c;
        }
    }
    for (int k = 0; k < 9; k++) {
        double v = s[k];
        for (int off = 32; off > 0; off >>= 1) v += __shfl_down(v, off, 64);
        s[k] = v;
    }
    if ((tid & 63) == 0)
        for (int k = 0; k < 9; k++) wsum[tid >> 6][k] = s[k];
    __syncthreads();
    if (tid < 9)
        partial[blockIdx.x * 9 + tid] =
            wsum[0][tid] + wsum[1][tid] + wsum[2][tid] + wsum[3][tid];
    __syncthreads();
    if (tid == 0) {
        __threadfence();                                  // release partials
        unsigned old = atomicAdd(done, 1u);               // device-scope ticket
        isLast = (old == RBLK - 1) ? 1 : 0;
    }
    __syncthreads();
    if (!isLast) return;
    __threadfence();                                      // acquire partials

    double t[9] = {0, 0, 0, 0, 0, 0, 0, 0, 0};
    for (int bb = tid; bb < RBLK; bb += 256)
        for (int k = 0; k < 9; k++) t[k] += partial[bb * 9 + k];
    for (int k = 0; k < 9; k++) {
        double v = t[k];
        for (int off = 32; off > 0; off >>= 1) v += __shfl_down(v, off, 64);
        t[k] = v;
    }
    if ((tid & 63) == 0)
        for (int k = 0; k < 9; k++) wsum[tid >> 6][k] = t[k];
    __syncthreads();
    if (tid == 0) {
        double acc[9];
        for (int k = 0; k < 9; k++)
            acc[k] = wsum[0][k] + wsum[1][k] + wsum[2][k] + wsum[3][k];
        double cnt_raw = acc[0];
        double cnt = cnt_raw > 1.0 ? cnt_raw : 1.0;
        double lxy  = acc[1] / cnt;
        double lwh  = acc[2] / cnt;
        double lgou = 1.0 - acc[3] / cnt;
        double liou = 1.0 - acc[4] / cnt;
        double icnt = acc[5] > 1.0 ? acc[5] : 1.0;
        double lbce = acc[6] / icnt;
        // gt_area = (tpf*ig).sum() == raw tp count (ig superset of tp), UNclamped
        double ldice = 1.0 - (2.0 * acc[7] + 1.0) / (acc[8] + cnt_raw + 1.0);
        double lconf = ldice + lbce;
        double tot = lconf + 2.0 * lgou + lwh + lxy;
        o[0] = (float)lxy;
        o[1] = (float)lwh;
        o[2] = (float)lconf;
        o[3] = (float)liou;
        o[4] = (float)lgou;
        o[5] = (float)tot;
    }
}

extern "C" void kernel_launch(void* const* d_in, const int* in_sizes, int n_in,
                              void* d_out, int out_size, void* d_ws, size_t ws_size,
                              hipStream_t stream) {
    const float* out_t = (const float*)d_in[0];  // [8,15,128,128]
    const float* gts   = (const float*)d_in[1];  // [64,5]
    char* ws = (char*)d_ws;
    size_t off = 0;
    unsigned* done    = (unsigned*)(ws + off);  off += 256;
    double*   partial = (double*)(ws + off);    off += (size_t)RBLK * 9 * 8;    // 18432
    float*    pval    = (float*)(ws + off);     off += (size_t)MGT * NCHD * 4;  // 49152
    int*      ppd     = (int*)(ws + off);       off += (size_t)MGT * NCHD * 4;  // 49152
    unsigned* tpbits  = (unsigned*)(ws + off);  off += (size_t)NB * NWRD * 4;   // 49152
    int*      pidx    = (int*)(ws + off);       off += (size_t)NTOT * 4;        // 1.5 MB
    off = (off + 15) & ~(size_t)15;
    float4*   pd      = (float4*)(ws + off);    off += (size_t)NTOT * 16;       // 6.3 MB
    float*    conf    = (float*)(ws + off);     off += (size_t)NTOT * 4;        // 1.5 MB
    float* o = (float*)d_out;

    k_decode<<<NTOT / 256, 256, 0, stream>>>(out_t, gts, pd, conf, pval, ppd, done);
    k_match <<<NB, MTH, 0, stream>>>(gts, pval, ppd, pd, tpbits, pidx);
    k_reduce<<<RBLK, 256, 0, stream>>>(gts, pd, conf, tpbits, pidx, partial, done, o);
}